// Round 6
// baseline (171.948 us; speedup 1.0000x reference)
//
#include <hip/hip_runtime.h>
#include <hip/hip_bf16.h>
#include <stdint.h>

// Problem constants
#define BS   8
#define CIN  256
#define COUT 256
#define SD   512
#define HH   64
#define WW   64
#define HP   66   // padded spatial dim

typedef __attribute__((ext_vector_type(8))) short short8;
typedef __attribute__((ext_vector_type(4))) float f32x4;

__device__ __forceinline__ unsigned short f2bf(float f) {
    __hip_bfloat16 h = __float2bfloat16(f);
    return *reinterpret_cast<unsigned short*>(&h);
}

typedef __attribute__((address_space(3))) unsigned int lds_u32_t;
typedef const __attribute__((address_space(1))) unsigned int glb_u32_t;

__device__ __forceinline__ void async16(const void* g, void* l) {
    __builtin_amdgcn_global_load_lds((glb_u32_t*)g, (lds_u32_t*)l, 16, 0, 0);
}

#define VMCNT(n) asm volatile("s_waitcnt vmcnt(" #n ")" ::: "memory")
// Anti-hoist guard used ONLY immediately after s_barrier.
#define SCHED_FENCE() __builtin_amdgcn_sched_barrier(0)

// ---------------------------------------------------------------------------
// K1: m[b,i] = s[b,:].aw[i,:] + ab[i] + 1
__global__ void k_style(const float* __restrict__ s, const float* __restrict__ aw,
                        const float* __restrict__ ab, float* __restrict__ m) {
    int b = blockIdx.x >> 3, chunk = blockIdx.x & 7;
    int tid = threadIdx.x;
    __shared__ float sv[SD];
    for (int d = tid; d < SD; d += 256) sv[d] = s[b * SD + d];
    __syncthreads();
    int il = tid >> 3, p = tid & 7;
    int i = chunk * 32 + il;
    const float4* awr = (const float4*)(aw + (size_t)i * SD + p * 64);
    float acc = 0.f;
#pragma unroll
    for (int d4 = 0; d4 < 16; ++d4) {
        float4 w4 = awr[d4];
        int d0 = p * 64 + d4 * 4;
        acc += w4.x * sv[d0] + w4.y * sv[d0 + 1] + w4.z * sv[d0 + 2] + w4.w * sv[d0 + 3];
    }
    acc += __shfl_xor(acc, 1);
    acc += __shfl_xor(acc, 2);
    acc += __shfl_xor(acc, 4);
    if (p == 0) m[b * CIN + i] = acc + ab[i] + 1.0f;
}

// ---------------------------------------------------------------------------
// K2: merged prep. Blocks [0,256): weight repack + dinv. Blocks [256,784):
// x modulate + NCHW fp32 -> zero-padded NHWC bf16 transpose.
__global__ void k_prep(const float* __restrict__ w, const float* __restrict__ m,
                       const float* __restrict__ x,
                       unsigned short* __restrict__ wb, float* __restrict__ dinv,
                       unsigned short* __restrict__ xp) {
    __shared__ float red[4][8];
    int tid = threadIdx.x;

    if (blockIdx.x < COUT) {
        int o = blockIdx.x, i = tid;
        const float* wp = w + ((size_t)o * CIN + i) * 9;
        float v[9];
        float q = 0.f;
#pragma unroll
        for (int t = 0; t < 9; ++t) { v[t] = wp[t]; q += v[t] * v[t]; }
#pragma unroll
        for (int t = 0; t < 9; ++t)
            wb[((size_t)t * COUT + o) * CIN + i] = f2bf(v[t]);

        float r[8];
#pragma unroll
        for (int b = 0; b < 8; ++b) {
            float mv = m[b * CIN + i];
            r[b] = q * mv * mv;
        }
#pragma unroll
        for (int b = 0; b < 8; ++b) {
            r[b] += __shfl_xor(r[b], 1);
            r[b] += __shfl_xor(r[b], 2);
            r[b] += __shfl_xor(r[b], 4);
            r[b] += __shfl_xor(r[b], 8);
            r[b] += __shfl_xor(r[b], 16);
            r[b] += __shfl_xor(r[b], 32);
        }
        int lane = i & 63, wid = i >> 6;
        if (lane == 0) {
#pragma unroll
            for (int b = 0; b < 8; ++b) red[wid][b] = r[b];
        }
        __syncthreads();
        if (i < 8) {
            float acc = red[0][i] + red[1][i] + red[2][i] + red[3][i];
            dinv[i * COUT + o] = rsqrtf(acc + 1e-8f);
        }
        return;
    }

    int bi = blockIdx.x - COUT;
    int b = bi / HP, yp = bi % HP;
    unsigned short* row = xp + ((size_t)(b * HP + yp)) * HP * CIN;

    if (yp == 0 || yp == HP - 1) {
        uint4 z = {0u, 0u, 0u, 0u};
        uint4* r = (uint4*)row;
        for (int j = tid; j < HP * CIN / 8; j += 256) r[j] = z;
        return;
    }
    int y = yp - 1;

    if (tid < 64) {
        uint4 z = {0u, 0u, 0u, 0u};
        if (tid < 32) ((uint4*)row)[tid] = z;
        else ((uint4*)(row + (size_t)(HP - 1) * CIN))[tid - 32] = z;
    }

#pragma unroll
    for (int it = 0; it < 2; ++it) {
        int u = it * 256 + tid;
        int x0 = (u & 15) * 4;
        int i0 = (u >> 4) * 8;
        float vv[8][4];
        float mv[8];
#pragma unroll
        for (int k = 0; k < 8; ++k) {
            *(float4*)vv[k] = *(const float4*)&x[(((size_t)b * CIN + i0 + k) * HH + y) * WW + x0];
            mv[k] = m[b * CIN + i0 + k];
        }
#pragma unroll
        for (int j = 0; j < 4; ++j) {
            short8 p;
#pragma unroll
            for (int k = 0; k < 8; ++k)
                p[k] = (short)f2bf(vv[k][j] * mv[k]);
            *(short8*)&row[(size_t)(x0 + j + 1) * CIN + i0] = p;
        }
    }
}

// ---------------------------------------------------------------------------
// K3: implicit GEMM conv, 256m x 64n tile — BARRIER-FREE inner loop.
// Rounds 1-4 post-mortem: 3 different intra-tap pipelines all landed at
// ~44us because the per-tap s_barrier phase-locks all 8 waves/CU, making
// the LDS pipe (1536cy/tap/CU) and MFMA pipe (1242cy/tap/CU) execute as a
// SUM regardless of intra-wave instruction order. Fix: eliminate the reason
// the barrier exists. B (wb, 1.18MB, L2-resident per XCD) is no longer
// staged in LDS at all — each wave loads its B fragments directly from
// global into NAMED registers (plain loads: the compiler tracks them and
// inserts precise counted vmcnt before use; no manual waits, no rule-18
// hazard). Within a kc the A LDS buffer is read-only, so the 9-tap loop
// has ZERO barriers: waves free-run and the pipes overlap via wave-level
// TLP (m114). Barriers remain only at the 4 A-restage boundaries.
// B prefetch: 1 tap ahead into the alternate named set (parity-unrolled
// taps, all indices compile-time — no arrays, no scratch).
// L2 budget: 512blk x 36taps x 32KB = 590MB over ~25us = 23.6TB/s < 34.5.
// (Round 6 = identical resubmit: Round-5 bench died to container-acquire
// infra failure; audit found no hang/fault mechanism — uniform barriers,
// boundary-exact addressing, layout equivalence verified.)
__global__ void __launch_bounds__(256, 2)
k_conv(const unsigned short* __restrict__ xp,
       const unsigned short* __restrict__ wb,
       const float* __restrict__ dinv,
       const float* __restrict__ bias,
       float* __restrict__ out) {
    __shared__ unsigned short Ar[3168 * 8];      // 50688 B: [6 rows][66 cols][8 x 16B]

    int bx = blockIdx.x;
    int mt = bx & 127;
    int n0 = (bx >> 7) << 6;      // 4 N-tiles of 64
    int m0 = mt << 8;             // 256 m per tile
    int b  = m0 >> 12;
    int y0 = (m0 >> 6) & 63;      // image row base (tile = rows y0..y0+3)

    int tid = threadIdx.x;
    int lane = tid & 63, w = tid >> 6;
    int quad = lane >> 4, mrow = lane & 15;

    f32x4 acc[4][4] = {};

    const unsigned short* xb = xp + (size_t)b * HP * HP * CIN;
    // Per-lane B base: row (n0+mrow), channel sub-offset quad*8.
    const unsigned short* wbase = wb + ((size_t)(n0 + mrow)) * CIN + quad * 8;

    auto stageA = [&](int kc) {
        int ch0 = kc * 64;
#pragma unroll
        for (int k = 0; k < 12; ++k) {
            int sA = k * 256 + tid;
            int rowA = sA / 528;
            int rem = sA - rowA * 528;
            int colA = rem >> 3, c4 = rem & 7;
            async16(xb + ((size_t)(y0 + rowA) * HP + colA) * CIN + ch0 + ((c4 ^ (colA & 7)) << 3),
                    &Ar[sA * 8]);
        }
        if (tid < 96) {   // tail: 3168 - 3072
            int sA = 3072 + tid;
            int rowA = sA / 528;
            int rem = sA - rowA * 528;
            int colA = rem >> 3, c4 = rem & 7;
            async16(xb + ((size_t)(y0 + rowA) * HP + colA) * CIN + ch0 + ((c4 ^ (colA & 7)) << 3),
                    &Ar[sA * 8]);
        }
    };

    // B fragment global load: tap T, k-chunk KC, half H, n-subtile J.
    // (channels (H*4+quad)*8..+7 of row n0+mrow+J*16 — identical data the
    // old LDS path delivered, verified vs its swizzle round-trip.)
#define LDB(T, KC, H, J) \
    (*(const short8*)(wbase + ((size_t)(T) * COUT + (J) * 16) * CIN + (KC) * 64 + (H) * 32))

#define LOADB(S, T, KC) do { \
    S##0 = LDB(T, KC, 0, 0); S##1 = LDB(T, KC, 0, 1); \
    S##2 = LDB(T, KC, 0, 2); S##3 = LDB(T, KC, 0, 3); \
    S##4 = LDB(T, KC, 1, 0); S##5 = LDB(T, KC, 1, 1); \
    S##6 = LDB(T, KC, 1, 2); S##7 = LDB(T, KC, 1, 3); } while (0)

    // A fragment LDS read (swizzled layout identical to prior rounds).
#define RDA(DY, DX, H, I) \
    (*(const short8*)&Ar[(size_t)((w + (DY)) * 528 + (mrow + (I) * 16 + (DX)) * 8 + \
        (((H) * 4 + quad) ^ ((mrow + (I) * 16 + (DX)) & 7))) * 8])

#define LOADA(T) do { \
    A0 = RDA((T) / 3, (T) % 3, 0, 0); A1 = RDA((T) / 3, (T) % 3, 0, 1); \
    A2 = RDA((T) / 3, (T) % 3, 0, 2); A3 = RDA((T) / 3, (T) % 3, 0, 3); \
    A4 = RDA((T) / 3, (T) % 3, 1, 0); A5 = RDA((T) / 3, (T) % 3, 1, 1); \
    A6 = RDA((T) / 3, (T) % 3, 1, 2); A7 = RDA((T) / 3, (T) % 3, 1, 3); } while (0)

#define MFMA1(a, bb, c) __builtin_amdgcn_mfma_f32_16x16x32_bf16(a, bb, c, 0, 0, 0)

#define TAPMFMA(S) do { \
    acc[0][0] = MFMA1(A0, S##0, acc[0][0]); acc[0][1] = MFMA1(A0, S##1, acc[0][1]); \
    acc[0][2] = MFMA1(A0, S##2, acc[0][2]); acc[0][3] = MFMA1(A0, S##3, acc[0][3]); \
    acc[1][0] = MFMA1(A1, S##0, acc[1][0]); acc[1][1] = MFMA1(A1, S##1, acc[1][1]); \
    acc[1][2] = MFMA1(A1, S##2, acc[1][2]); acc[1][3] = MFMA1(A1, S##3, acc[1][3]); \
    acc[2][0] = MFMA1(A2, S##0, acc[2][0]); acc[2][1] = MFMA1(A2, S##1, acc[2][1]); \
    acc[2][2] = MFMA1(A2, S##2, acc[2][2]); acc[2][3] = MFMA1(A2, S##3, acc[2][3]); \
    acc[3][0] = MFMA1(A3, S##0, acc[3][0]); acc[3][1] = MFMA1(A3, S##1, acc[3][1]); \
    acc[3][2] = MFMA1(A3, S##2, acc[3][2]); acc[3][3] = MFMA1(A3, S##3, acc[3][3]); \
    acc[0][0] = MFMA1(A4, S##4, acc[0][0]); acc[0][1] = MFMA1(A4, S##5, acc[0][1]); \
    acc[0][2] = MFMA1(A4, S##6, acc[0][2]); acc[0][3] = MFMA1(A4, S##7, acc[0][3]); \
    acc[1][0] = MFMA1(A5, S##4, acc[1][0]); acc[1][1] = MFMA1(A5, S##5, acc[1][1]); \
    acc[1][2] = MFMA1(A5, S##6, acc[1][2]); acc[1][3] = MFMA1(A5, S##7, acc[1][3]); \
    acc[2][0] = MFMA1(A6, S##4, acc[2][0]); acc[2][1] = MFMA1(A6, S##5, acc[2][1]); \
    acc[2][2] = MFMA1(A6, S##6, acc[2][2]); acc[2][3] = MFMA1(A6, S##7, acc[2][3]); \
    acc[3][0] = MFMA1(A7, S##4, acc[3][0]); acc[3][1] = MFMA1(A7, S##5, acc[3][1]); \
    acc[3][2] = MFMA1(A7, S##6, acc[3][2]); acc[3][3] = MFMA1(A7, S##7, acc[3][3]); } while (0)

    // Tap body: prefetch next tap's B into NS, read A frags, MFMA with CS.
    // No barriers, no manual waits — compiler inserts precise counted vmcnt
    // for the tracked register loads and lgkmcnt for the ds_reads.
#define TAP(T, CS, NS) do { \
    if ((T) < 8) LOADB(NS, (T) + 1, kc); \
    LOADA(T); \
    TAPMFMA(CS); } while (0)

    // Named register fragment sets.
    short8 P0, P1, P2, P3, P4, P5, P6, P7;
    short8 Q0, Q1, Q2, Q3, Q4, Q5, Q6, Q7;
    short8 A0, A1, A2, A3, A4, A5, A6, A7;

    // Prologue: stage A(0) via DMA, load tap-0 B into P, drain, join.
    stageA(0);
    LOADB(P, 0, 0);
    VMCNT(0);
    __builtin_amdgcn_s_barrier();
    SCHED_FENCE();

#pragma unroll 1
    for (int kc = 0; kc < 4; ++kc) {
        TAP(0, P, Q); TAP(1, Q, P); TAP(2, P, Q);
        TAP(3, Q, P); TAP(4, P, Q); TAP(5, Q, P);
        TAP(6, P, Q); TAP(7, Q, P); TAP(8, P, Q);

        if (kc < 3) {
            // A restage boundary: all waves consumed their Ar reads (MFMAs
            // force lgkmcnt before barrier). Overwrite Ar, reload tap-0 B
            // for next kc into P, drain DMA+loads, rejoin.
            __builtin_amdgcn_s_barrier();
            SCHED_FENCE();
            stageA(kc + 1);
            LOADB(P, 0, kc + 1);
            VMCNT(0);
            __builtin_amdgcn_s_barrier();
            SCHED_FENCE();
        }
    }

#undef TAP
#undef TAPMFMA
#undef MFMA1
#undef LOADA
#undef RDA
#undef LOADB
#undef LDB

    // ---- Epilogue: *dinv + bias. Wave w owns image row y0+w.
    // C/D layout: n(col) = mrow, x = quad*4 + reg + i*16.
    int y = y0 + w;
#pragma unroll
    for (int j = 0; j < 4; ++j) {
        int o = n0 + mrow + j * 16;
        float dv = dinv[b * COUT + o];
        float bv = bias[o];
#pragma unroll
        for (int i = 0; i < 4; ++i) {
            int xx = i * 16 + quad * 4;
            f32x4 v = acc[i][j] * dv + bv;
            *(f32x4*)(out + (((size_t)(b * COUT + o) * HH + y) * WW + xx)) = v;
        }
    }
}

// ---------------------------------------------------------------------------
extern "C" void kernel_launch(void* const* d_in, const int* in_sizes, int n_in,
                              void* d_out, int out_size, void* d_ws, size_t ws_size,
                              hipStream_t stream) {
    const float* x    = (const float*)d_in[0];  // [8,256,64,64]
    const float* s    = (const float*)d_in[1];  // [8,512]
    const float* w    = (const float*)d_in[2];  // [256,256,3,3]
    const float* bias = (const float*)d_in[3];  // [256,1,1]
    const float* aw   = (const float*)d_in[4];  // [256,512]
    const float* ab   = (const float*)d_in[5];  // [256]
    float* out = (float*)d_out;

    char* ws = (char*)d_ws;
    float* m            = (float*)(ws + 0);                 //  8 KB [8][256]
    float* dinv         = (float*)(ws + 8192);              //  8 KB [8][256]
    unsigned short* wb  = (unsigned short*)(ws + 16384);    // 1.18 MB [9][256][256]
    unsigned short* xpb = (unsigned short*)(ws + 1196032);  // 17.8 MB [8][66][66][256]

    k_style<<<64, 256, 0, stream>>>(s, aw, ab, m);
    k_prep<<<COUT + BS * HP, 256, 0, stream>>>(w, m, x, wb, dinv, xpb);
    k_conv<<<512, 256, 0, stream>>>(xpb, wb, dinv, bias, out);
}

// Round 7
// 144.732 us; speedup vs baseline: 1.1880x; 1.1880x over previous
//
#include <hip/hip_runtime.h>
#include <hip/hip_bf16.h>
#include <stdint.h>

// Problem constants
#define BS   8
#define CIN  256
#define COUT 256
#define SD   512
#define HH   64
#define WW   64
#define HP   66   // padded spatial dim

typedef __attribute__((ext_vector_type(8))) short short8;
typedef __attribute__((ext_vector_type(4))) float f32x4;

__device__ __forceinline__ unsigned short f2bf(float f) {
    __hip_bfloat16 h = __float2bfloat16(f);
    return *reinterpret_cast<unsigned short*>(&h);
}

typedef __attribute__((address_space(3))) unsigned int lds_u32_t;
typedef const __attribute__((address_space(1))) unsigned int glb_u32_t;

__device__ __forceinline__ void async16(const void* g, void* l) {
    __builtin_amdgcn_global_load_lds((glb_u32_t*)g, (lds_u32_t*)l, 16, 0, 0);
}

// ---------------------------------------------------------------------------
// K1: m[b,i] = s[b,:].aw[i,:] + ab[i] + 1
__global__ void k_style(const float* __restrict__ s, const float* __restrict__ aw,
                        const float* __restrict__ ab, float* __restrict__ m) {
    int b = blockIdx.x >> 3, chunk = blockIdx.x & 7;
    int tid = threadIdx.x;
    __shared__ float sv[SD];
    for (int d = tid; d < SD; d += 256) sv[d] = s[b * SD + d];
    __syncthreads();
    int il = tid >> 3, p = tid & 7;
    int i = chunk * 32 + il;
    const float4* awr = (const float4*)(aw + (size_t)i * SD + p * 64);
    float acc = 0.f;
#pragma unroll
    for (int d4 = 0; d4 < 16; ++d4) {
        float4 w4 = awr[d4];
        int d0 = p * 64 + d4 * 4;
        acc += w4.x * sv[d0] + w4.y * sv[d0 + 1] + w4.z * sv[d0 + 2] + w4.w * sv[d0 + 3];
    }
    acc += __shfl_xor(acc, 1);
    acc += __shfl_xor(acc, 2);
    acc += __shfl_xor(acc, 4);
    if (p == 0) m[b * CIN + i] = acc + ab[i] + 1.0f;
}

// ---------------------------------------------------------------------------
// K2: merged prep. Blocks [0,256): weight repack + dinv. Blocks [256,784):
// x modulate + NCHW fp32 -> zero-padded NHWC bf16 transpose.
__global__ void k_prep(const float* __restrict__ w, const float* __restrict__ m,
                       const float* __restrict__ x,
                       unsigned short* __restrict__ wb, float* __restrict__ dinv,
                       unsigned short* __restrict__ xp) {
    __shared__ float red[4][8];
    int tid = threadIdx.x;

    if (blockIdx.x < COUT) {
        int o = blockIdx.x, i = tid;
        const float* wp = w + ((size_t)o * CIN + i) * 9;
        float v[9];
        float q = 0.f;
#pragma unroll
        for (int t = 0; t < 9; ++t) { v[t] = wp[t]; q += v[t] * v[t]; }
#pragma unroll
        for (int t = 0; t < 9; ++t)
            wb[((size_t)t * COUT + o) * CIN + i] = f2bf(v[t]);

        float r[8];
#pragma unroll
        for (int b = 0; b < 8; ++b) {
            float mv = m[b * CIN + i];
            r[b] = q * mv * mv;
        }
#pragma unroll
        for (int b = 0; b < 8; ++b) {
            r[b] += __shfl_xor(r[b], 1);
            r[b] += __shfl_xor(r[b], 2);
            r[b] += __shfl_xor(r[b], 4);
            r[b] += __shfl_xor(r[b], 8);
            r[b] += __shfl_xor(r[b], 16);
            r[b] += __shfl_xor(r[b], 32);
        }
        int lane = i & 63, wid = i >> 6;
        if (lane == 0) {
#pragma unroll
            for (int b = 0; b < 8; ++b) red[wid][b] = r[b];
        }
        __syncthreads();
        if (i < 8) {
            float acc = red[0][i] + red[1][i] + red[2][i] + red[3][i];
            dinv[i * COUT + o] = rsqrtf(acc + 1e-8f);
        }
        return;
    }

    int bi = blockIdx.x - COUT;
    int b = bi / HP, yp = bi % HP;
    unsigned short* row = xp + ((size_t)(b * HP + yp)) * HP * CIN;

    if (yp == 0 || yp == HP - 1) {
        uint4 z = {0u, 0u, 0u, 0u};
        uint4* r = (uint4*)row;
        for (int j = tid; j < HP * CIN / 8; j += 256) r[j] = z;
        return;
    }
    int y = yp - 1;

    if (tid < 64) {
        uint4 z = {0u, 0u, 0u, 0u};
        if (tid < 32) ((uint4*)row)[tid] = z;
        else ((uint4*)(row + (size_t)(HP - 1) * CIN))[tid - 32] = z;
    }

#pragma unroll
    for (int it = 0; it < 2; ++it) {
        int u = it * 256 + tid;
        int x0 = (u & 15) * 4;
        int i0 = (u >> 4) * 8;
        float vv[8][4];
        float mv[8];
#pragma unroll
        for (int k = 0; k < 8; ++k) {
            *(float4*)vv[k] = *(const float4*)&x[(((size_t)b * CIN + i0 + k) * HH + y) * WW + x0];
            mv[k] = m[b * CIN + i0 + k];
        }
#pragma unroll
        for (int j = 0; j < 4; ++j) {
            short8 p;
#pragma unroll
            for (int k = 0; k < 8; ++k)
                p[k] = (short)f2bf(vv[k][j] * mv[k]);
            *(short8*)&row[(size_t)(x0 + j + 1) * CIN + i0] = p;
        }
    }
}

// ---------------------------------------------------------------------------
// K3: implicit GEMM conv, 256m x 64n tile, 512 threads (8 waves, 4m x 2n),
// BARRIER-FREE 9-tap inner loop.
// Rounds 1-6 post-mortem: per-tap barriers phase-lock all waves, forcing
// LDS-read and MFMA pipes to execute as a SUM (2778cy/tap measured); direct
// global B-loads (R6) trade that for worse scattered-L2 latency (82us).
// Fix: stage B for ALL 9 taps of a k-chunk into LDS at once (72KB) next to
// A (50.7KB) = 124.4KB, 1 block/CU. Within a kc both LDS regions are
// READ-ONLY, so the 9-tap loop has zero barriers/waits: 8 waves free-run
// and the pipes overlap via wave TLP (m114). Only 4 kc boundaries sync
// (__syncthreads' vmcnt(0) drain is genuinely required there for the DMA).
// Wave split 4m x 2n (wave = 64m x 32n): 12 ds_read_b128 + 16 MFMA per
// wave-tap (was 16 + 32). Per-CU per-tap: LDS 1152cy, MFMA 620cy ->
// floor max=1152cy/tap (~17us), worst-case sum=1772cy/tap (~27us) — both
// beat the 44us attractor. Swizzle formulas inherited (0 conflicts).
__global__ void __launch_bounds__(512, 2)
k_conv(const unsigned short* __restrict__ xp,
       const unsigned short* __restrict__ wb,
       const float* __restrict__ dinv,
       const float* __restrict__ bias,
       float* __restrict__ out) {
    __shared__ unsigned short Ar[3168 * 8];      // 50688 B: [6 rows][66 cols][8 x 16B]
    __shared__ unsigned short Bs[4608 * 8];      // 73728 B: [9 taps][64 rows][8 x 16B]

    int bx = blockIdx.x;
    int mt = bx & 127;
    int n0 = (bx >> 7) << 6;      // 4 N-tiles of 64
    int m0 = mt << 8;             // 256 m per tile
    int b  = m0 >> 12;
    int y0 = (m0 >> 6) & 63;      // image row base (tile = rows y0..y0+3)

    int tid = threadIdx.x;
    int lane = tid & 63, w = tid >> 6;      // w in 0..7
    int wm = w >> 1, wn = w & 1;            // 4m x 2n wave grid
    int quad = lane >> 4, mrow = lane & 15;

    f32x4 acc[4][2] = {};

    const unsigned short* xb = xp + (size_t)b * HP * HP * CIN;

    auto stageA = [&](int kc) {
        int ch0 = kc * 64;
#pragma unroll
        for (int k = 0; k < 6; ++k) {
            int sA = k * 512 + tid;
            int rowA = sA / 528;
            int rem = sA - rowA * 528;
            int colA = rem >> 3, c4 = rem & 7;
            async16(xb + ((size_t)(y0 + rowA) * HP + colA) * CIN + ch0 + ((c4 ^ (colA & 7)) << 3),
                    &Ar[sA * 8]);
        }
        if (tid < 96) {   // tail: 3168 - 3072
            int sA = 3072 + tid;
            int rowA = sA / 528;
            int rem = sA - rowA * 528;
            int colA = rem >> 3, c4 = rem & 7;
            async16(xb + ((size_t)(y0 + rowA) * HP + colA) * CIN + ch0 + ((c4 ^ (colA & 7)) << 3),
                    &Ar[sA * 8]);
        }
    };

    // Stage all 9 taps' B tiles for k-chunk kc. Tap t = loop index k;
    // thread stages chunk tid of tap k (512 chunks = 8KB per tap).
    auto stageBall = [&](int kc) {
#pragma unroll
        for (int k = 0; k < 9; ++k) {
            int rowB = tid >> 3, c4 = tid & 7;
            async16(wb + ((size_t)k * COUT + n0 + rowB) * CIN + kc * 64 + ((c4 ^ (rowB & 7)) << 3),
                    &Bs[(k * 512 + tid) * 8]);
        }
    };

#pragma unroll 1
    for (int kc = 0; kc < 4; ++kc) {
        if (kc) __syncthreads();   // join: all waves done reading prev kc
        stageA(kc);
        stageBall(kc);
        __syncthreads();           // drains vmcnt(0) -> DMA landed, all join

        // ---- 9 taps, ZERO barriers: Ar/Bs read-only within this kc.
#pragma unroll
        for (int t = 0; t < 9; ++t) {
            int dy = t / 3, dx = t - dy * 3;
            int arow = wm + dy;

            short8 af[2][4], bf[2][2];
#pragma unroll
            for (int h = 0; h < 2; ++h)
#pragma unroll
                for (int i = 0; i < 4; ++i) {
                    int col = mrow + i * 16 + dx;
                    int chunk = arow * 528 + col * 8 + ((h * 4 + quad) ^ (col & 7));
                    af[h][i] = *(const short8*)&Ar[chunk * 8];
                }
#pragma unroll
            for (int h = 0; h < 2; ++h)
#pragma unroll
                for (int j = 0; j < 2; ++j) {
                    int rowB = wn * 32 + mrow + j * 16;
                    int chunk = t * 512 + rowB * 8 + ((h * 4 + quad) ^ (rowB & 7));
                    bf[h][j] = *(const short8*)&Bs[chunk * 8];
                }
#pragma unroll
            for (int h = 0; h < 2; ++h)
#pragma unroll
                for (int i = 0; i < 4; ++i)
#pragma unroll
                    for (int j = 0; j < 2; ++j)
                        acc[i][j] = __builtin_amdgcn_mfma_f32_16x16x32_bf16(
                            af[h][i], bf[h][j], acc[i][j], 0, 0, 0);
        }
    }

    // ---- Epilogue: *dinv + bias. Wave (wm,wn) owns image row y0+wm,
    // channels n0+wn*32..+31. C/D: n(col) = mrow, x = quad*4 + reg + i*16.
    int y = y0 + wm;
#pragma unroll
    for (int j = 0; j < 2; ++j) {
        int o = n0 + wn * 32 + mrow + j * 16;
        float dv = dinv[b * COUT + o];
        float bv = bias[o];
#pragma unroll
        for (int i = 0; i < 4; ++i) {
            int xx = i * 16 + quad * 4;
            f32x4 v = acc[i][j] * dv + bv;
            *(f32x4*)(out + (((size_t)(b * COUT + o) * HH + y) * WW + xx)) = v;
        }
    }
}

// ---------------------------------------------------------------------------
extern "C" void kernel_launch(void* const* d_in, const int* in_sizes, int n_in,
                              void* d_out, int out_size, void* d_ws, size_t ws_size,
                              hipStream_t stream) {
    const float* x    = (const float*)d_in[0];  // [8,256,64,64]
    const float* s    = (const float*)d_in[1];  // [8,512]
    const float* w    = (const float*)d_in[2];  // [256,256,3,3]
    const float* bias = (const float*)d_in[3];  // [256,1,1]
    const float* aw   = (const float*)d_in[4];  // [256,512]
    const float* ab   = (const float*)d_in[5];  // [256]
    float* out = (float*)d_out;

    char* ws = (char*)d_ws;
    float* m            = (float*)(ws + 0);                 //  8 KB [8][256]
    float* dinv         = (float*)(ws + 8192);              //  8 KB [8][256]
    unsigned short* wb  = (unsigned short*)(ws + 16384);    // 1.18 MB [9][256][256]
    unsigned short* xpb = (unsigned short*)(ws + 1196032);  // 17.8 MB [8][66][66][256]

    k_style<<<64, 256, 0, stream>>>(s, aw, ab, m);
    k_prep<<<COUT + BS * HP, 256, 0, stream>>>(w, m, x, wb, dinv, xpb);
    k_conv<<<512, 512, 0, stream>>>(xpb, wb, dinv, bias, out);
}

// Round 8
// 143.069 us; speedup vs baseline: 1.2019x; 1.0116x over previous
//
#include <hip/hip_runtime.h>
#include <hip/hip_bf16.h>
#include <stdint.h>

// Problem constants
#define BS   8
#define CIN  256
#define COUT 256
#define SD   512
#define HH   64
#define WW   64
#define HP   66   // padded spatial dim

typedef __attribute__((ext_vector_type(8))) short short8;
typedef __attribute__((ext_vector_type(4))) float f32x4;

__device__ __forceinline__ unsigned short f2bf(float f) {
    __hip_bfloat16 h = __float2bfloat16(f);
    return *reinterpret_cast<unsigned short*>(&h);
}

typedef __attribute__((address_space(3))) unsigned int lds_u32_t;
typedef const __attribute__((address_space(1))) unsigned int glb_u32_t;

__device__ __forceinline__ void async16(const void* g, void* l) {
    __builtin_amdgcn_global_load_lds((glb_u32_t*)g, (lds_u32_t*)l, 16, 0, 0);
}

// ---------------------------------------------------------------------------
// K1: m[b,i] = s[b,:].aw[i,:] + ab[i] + 1
__global__ void k_style(const float* __restrict__ s, const float* __restrict__ aw,
                        const float* __restrict__ ab, float* __restrict__ m) {
    int b = blockIdx.x >> 3, chunk = blockIdx.x & 7;
    int tid = threadIdx.x;
    __shared__ float sv[SD];
    for (int d = tid; d < SD; d += 256) sv[d] = s[b * SD + d];
    __syncthreads();
    int il = tid >> 3, p = tid & 7;
    int i = chunk * 32 + il;
    const float4* awr = (const float4*)(aw + (size_t)i * SD + p * 64);
    float acc = 0.f;
#pragma unroll
    for (int d4 = 0; d4 < 16; ++d4) {
        float4 w4 = awr[d4];
        int d0 = p * 64 + d4 * 4;
        acc += w4.x * sv[d0] + w4.y * sv[d0 + 1] + w4.z * sv[d0 + 2] + w4.w * sv[d0 + 3];
    }
    acc += __shfl_xor(acc, 1);
    acc += __shfl_xor(acc, 2);
    acc += __shfl_xor(acc, 4);
    if (p == 0) m[b * CIN + i] = acc + ab[i] + 1.0f;
}

// ---------------------------------------------------------------------------
// K2: merged prep. Blocks [0,256): weight repack + dinv. Blocks [256,784):
// x modulate + NCHW fp32 -> zero-padded NHWC bf16 transpose.
__global__ void k_prep(const float* __restrict__ w, const float* __restrict__ m,
                       const float* __restrict__ x,
                       unsigned short* __restrict__ wb, float* __restrict__ dinv,
                       unsigned short* __restrict__ xp) {
    __shared__ float red[4][8];
    int tid = threadIdx.x;

    if (blockIdx.x < COUT) {
        int o = blockIdx.x, i = tid;
        const float* wp = w + ((size_t)o * CIN + i) * 9;
        float v[9];
        float q = 0.f;
#pragma unroll
        for (int t = 0; t < 9; ++t) { v[t] = wp[t]; q += v[t] * v[t]; }
#pragma unroll
        for (int t = 0; t < 9; ++t)
            wb[((size_t)t * COUT + o) * CIN + i] = f2bf(v[t]);

        float r[8];
#pragma unroll
        for (int b = 0; b < 8; ++b) {
            float mv = m[b * CIN + i];
            r[b] = q * mv * mv;
        }
#pragma unroll
        for (int b = 0; b < 8; ++b) {
            r[b] += __shfl_xor(r[b], 1);
            r[b] += __shfl_xor(r[b], 2);
            r[b] += __shfl_xor(r[b], 4);
            r[b] += __shfl_xor(r[b], 8);
            r[b] += __shfl_xor(r[b], 16);
            r[b] += __shfl_xor(r[b], 32);
        }
        int lane = i & 63, wid = i >> 6;
        if (lane == 0) {
#pragma unroll
            for (int b = 0; b < 8; ++b) red[wid][b] = r[b];
        }
        __syncthreads();
        if (i < 8) {
            float acc = red[0][i] + red[1][i] + red[2][i] + red[3][i];
            dinv[i * COUT + o] = rsqrtf(acc + 1e-8f);
        }
        return;
    }

    int bi = blockIdx.x - COUT;
    int b = bi / HP, yp = bi % HP;
    unsigned short* row = xp + ((size_t)(b * HP + yp)) * HP * CIN;

    if (yp == 0 || yp == HP - 1) {
        uint4 z = {0u, 0u, 0u, 0u};
        uint4* r = (uint4*)row;
        for (int j = tid; j < HP * CIN / 8; j += 256) r[j] = z;
        return;
    }
    int y = yp - 1;

    if (tid < 64) {
        uint4 z = {0u, 0u, 0u, 0u};
        if (tid < 32) ((uint4*)row)[tid] = z;
        else ((uint4*)(row + (size_t)(HP - 1) * CIN))[tid - 32] = z;
    }

#pragma unroll
    for (int it = 0; it < 2; ++it) {
        int u = it * 256 + tid;
        int x0 = (u & 15) * 4;
        int i0 = (u >> 4) * 8;
        float vv[8][4];
        float mv[8];
#pragma unroll
        for (int k = 0; k < 8; ++k) {
            *(float4*)vv[k] = *(const float4*)&x[(((size_t)b * CIN + i0 + k) * HH + y) * WW + x0];
            mv[k] = m[b * CIN + i0 + k];
        }
#pragma unroll
        for (int j = 0; j < 4; ++j) {
            short8 p;
#pragma unroll
            for (int k = 0; k < 8; ++k)
                p[k] = (short)f2bf(vv[k][j] * mv[k]);
            *(short8*)&row[(size_t)(x0 + j + 1) * CIN + i0] = p;
        }
    }
}

// ---------------------------------------------------------------------------
// K3: implicit GEMM conv — 512m x 64n block, 512 threads, 8 waves of 64x64,
// barrier-free 9-tap loop + named-register double-buffer pipeline.
// Round-8 synthesis of what measurement validated / refuted:
//  * 64x64 wave shape (reads/MFMA = 0.5; R7's 64x32 was 0.75 -> LDS 83k cy
//    vs 55.3k per CU. Baseline already had the good shape).
//  * B staged for ALL 9 taps (72KB) + A (10 rows, 84.5KB) = 158.2KB LDS,
//    1 block/CU, grid = 256 = exactly 1 block/CU, no second round.
//    Within a kc both LDS regions read-only -> ZERO barriers in tap loop.
//  * Explicit 2-set named-register pipeline (R4 technique, scratch-safe):
//    tap t issues tap t+1's 16 ds_reads BEFORE tap t's 32 MFMAs; per-wave
//    lgkmcnt stalls vanish; no barrier forces the inter-wave convoy that
//    defeated R2/R4/R7.
// Per-CU floor: LDS 128 b128/tap x 36 taps x 12cy = 55.3k cy (=23us) with
// MFMA 44.7k cy hidden under it + ~11k cy staging exposed -> ~27us target.
// XCD locality: same-A blocks are bx, bx+64, bx+128, bx+192 == bx mod 8.
__global__ void __launch_bounds__(512, 2)
k_conv(const unsigned short* __restrict__ xp,
       const unsigned short* __restrict__ wb,
       const float* __restrict__ dinv,
       const float* __restrict__ bias,
       float* __restrict__ out) {
    __shared__ unsigned short Ar[5280 * 8];      // 84480 B: [10 rows][66 cols][8 x 16B]
    __shared__ unsigned short Bs[4608 * 8];      // 73728 B: [9 taps][64 rows][8 x 16B]

    int bx = blockIdx.x;
    int mt = bx & 63;             // 64 m-tiles (8 batches x 8 row-groups)
    int n0 = (bx >> 6) << 6;      // 4 N-tiles of 64
    int b  = mt >> 3;
    int y0 = (mt & 7) << 3;       // image row base (tile = rows y0..y0+7)

    int tid = threadIdx.x;
    int lane = tid & 63, w = tid >> 6;      // wave 0..7 owns image row y0+w
    int quad = lane >> 4, mrow = lane & 15;

    f32x4 acc[4][4] = {};

    const unsigned short* xb = xp + (size_t)b * HP * HP * CIN;

    // Stage A: 10 padded rows (y0..y0+9) x 66 cols x 64 ch = 5280 chunks.
    auto stageA = [&](int kc) {
        int ch0 = kc * 64;
#pragma unroll
        for (int k = 0; k < 10; ++k) {
            int sA = k * 512 + tid;
            int rowA = sA / 528;
            int rem = sA - rowA * 528;
            int colA = rem >> 3, c4 = rem & 7;
            async16(xb + ((size_t)(y0 + rowA) * HP + colA) * CIN + ch0 + ((c4 ^ (colA & 7)) << 3),
                    &Ar[sA * 8]);
        }
        if (tid < 160) {   // tail: 5280 - 5120
            int sA = 5120 + tid;
            int rowA = sA / 528;
            int rem = sA - rowA * 528;
            int colA = rem >> 3, c4 = rem & 7;
            async16(xb + ((size_t)(y0 + rowA) * HP + colA) * CIN + ch0 + ((c4 ^ (colA & 7)) << 3),
                    &Ar[sA * 8]);
        }
    };

    // Stage all 9 taps' B tiles for k-chunk kc (each tap: 64 rows x 64 ch).
    auto stageBall = [&](int kc) {
#pragma unroll
        for (int k = 0; k < 9; ++k) {
            int rowB = tid >> 3, c4 = tid & 7;
            async16(wb + ((size_t)k * COUT + n0 + rowB) * CIN + kc * 64 + ((c4 ^ (rowB & 7)) << 3),
                    &Bs[(k * 512 + tid) * 8]);
        }
    };

    // Fragment loads (value expressions, compile-time indices only).
#define LDA_(T, H, I) \
    (*(const short8*)&Ar[(size_t)((w + (T) / 3) * 528 + (mrow + (I) * 16 + (T) % 3) * 8 + \
        (((H) * 4 + quad) ^ ((mrow + (I) * 16 + (T) % 3) & 7))) * 8])
#define LDB_(T, H, J) \
    (*(const short8*)&Bs[(size_t)((T) * 512 + (mrow + (J) * 16) * 8 + \
        (((H) * 4 + quad) ^ ((mrow + (J) * 16) & 7))) * 8])

#define LOADSET(S, T) do { \
    S##A0 = LDA_(T, 0, 0); S##A1 = LDA_(T, 0, 1); S##A2 = LDA_(T, 0, 2); S##A3 = LDA_(T, 0, 3); \
    S##A4 = LDA_(T, 1, 0); S##A5 = LDA_(T, 1, 1); S##A6 = LDA_(T, 1, 2); S##A7 = LDA_(T, 1, 3); \
    S##B0 = LDB_(T, 0, 0); S##B1 = LDB_(T, 0, 1); S##B2 = LDB_(T, 0, 2); S##B3 = LDB_(T, 0, 3); \
    S##B4 = LDB_(T, 1, 0); S##B5 = LDB_(T, 1, 1); S##B6 = LDB_(T, 1, 2); S##B7 = LDB_(T, 1, 3); } while (0)

#define MFMA1(a, bb, c) __builtin_amdgcn_mfma_f32_16x16x32_bf16(a, bb, c, 0, 0, 0)

#define MFMASET(S) do { \
    acc[0][0] = MFMA1(S##A0, S##B0, acc[0][0]); acc[0][1] = MFMA1(S##A0, S##B1, acc[0][1]); \
    acc[0][2] = MFMA1(S##A0, S##B2, acc[0][2]); acc[0][3] = MFMA1(S##A0, S##B3, acc[0][3]); \
    acc[1][0] = MFMA1(S##A1, S##B0, acc[1][0]); acc[1][1] = MFMA1(S##A1, S##B1, acc[1][1]); \
    acc[1][2] = MFMA1(S##A1, S##B2, acc[1][2]); acc[1][3] = MFMA1(S##A1, S##B3, acc[1][3]); \
    acc[2][0] = MFMA1(S##A2, S##B0, acc[2][0]); acc[2][1] = MFMA1(S##A2, S##B1, acc[2][1]); \
    acc[2][2] = MFMA1(S##A2, S##B2, acc[2][2]); acc[2][3] = MFMA1(S##A2, S##B3, acc[2][3]); \
    acc[3][0] = MFMA1(S##A3, S##B0, acc[3][0]); acc[3][1] = MFMA1(S##A3, S##B1, acc[3][1]); \
    acc[3][2] = MFMA1(S##A3, S##B2, acc[3][2]); acc[3][3] = MFMA1(S##A3, S##B3, acc[3][3]); \
    acc[0][0] = MFMA1(S##A4, S##B4, acc[0][0]); acc[0][1] = MFMA1(S##A4, S##B5, acc[0][1]); \
    acc[0][2] = MFMA1(S##A4, S##B6, acc[0][2]); acc[0][3] = MFMA1(S##A4, S##B7, acc[0][3]); \
    acc[1][0] = MFMA1(S##A5, S##B4, acc[1][0]); acc[1][1] = MFMA1(S##A5, S##B5, acc[1][1]); \
    acc[1][2] = MFMA1(S##A5, S##B6, acc[1][2]); acc[1][3] = MFMA1(S##A5, S##B7, acc[1][3]); \
    acc[2][0] = MFMA1(S##A6, S##B4, acc[2][0]); acc[2][1] = MFMA1(S##A6, S##B5, acc[2][1]); \
    acc[2][2] = MFMA1(S##A6, S##B6, acc[2][2]); acc[2][3] = MFMA1(S##A6, S##B7, acc[2][3]); \
    acc[3][0] = MFMA1(S##A7, S##B4, acc[3][0]); acc[3][1] = MFMA1(S##A7, S##B5, acc[3][1]); \
    acc[3][2] = MFMA1(S##A7, S##B6, acc[3][2]); acc[3][3] = MFMA1(S##A7, S##B7, acc[3][3]); } while (0)

    // Two named fragment sets (P current / Q next), individually named regs.
    short8 PA0, PA1, PA2, PA3, PA4, PA5, PA6, PA7;
    short8 PB0, PB1, PB2, PB3, PB4, PB5, PB6, PB7;
    short8 QA0, QA1, QA2, QA3, QA4, QA5, QA6, QA7;
    short8 QB0, QB1, QB2, QB3, QB4, QB5, QB6, QB7;

#pragma unroll 1
    for (int kc = 0; kc < 4; ++kc) {
        if (kc) __syncthreads();   // all waves done reading prev kc's LDS
        stageA(kc);
        stageBall(kc);
        __syncthreads();           // vmcnt(0) drain: DMA landed; all join

        // 9 taps, zero barriers. Pipeline: load tap t+1 before MFMA tap t.
        LOADSET(P, 0);
        LOADSET(Q, 1); MFMASET(P);
        LOADSET(P, 2); MFMASET(Q);
        LOADSET(Q, 3); MFMASET(P);
        LOADSET(P, 4); MFMASET(Q);
        LOADSET(Q, 5); MFMASET(P);
        LOADSET(P, 6); MFMASET(Q);
        LOADSET(Q, 7); MFMASET(P);
        LOADSET(P, 8); MFMASET(Q);
        MFMASET(P);
    }

#undef MFMASET
#undef MFMA1
#undef LOADSET
#undef LDB_
#undef LDA_

    // ---- Epilogue: *dinv + bias. Wave w owns image row y0+w, all 64 n.
    // C/D layout: n(col) = mrow, x = quad*4 + reg + i*16.
    int y = y0 + w;
#pragma unroll
    for (int j = 0; j < 4; ++j) {
        int o = n0 + mrow + j * 16;
        float dv = dinv[b * COUT + o];
        float bv = bias[o];
#pragma unroll
        for (int i = 0; i < 4; ++i) {
            int xx = i * 16 + quad * 4;
            f32x4 v = acc[i][j] * dv + bv;
            *(f32x4*)(out + (((size_t)(b * COUT + o) * HH + y) * WW + xx)) = v;
        }
    }
}

// ---------------------------------------------------------------------------
extern "C" void kernel_launch(void* const* d_in, const int* in_sizes, int n_in,
                              void* d_out, int out_size, void* d_ws, size_t ws_size,
                              hipStream_t stream) {
    const float* x    = (const float*)d_in[0];  // [8,256,64,64]
    const float* s    = (const float*)d_in[1];  // [8,512]
    const float* w    = (const float*)d_in[2];  // [256,256,3,3]
    const float* bias = (const float*)d_in[3];  // [256,1,1]
    const float* aw   = (const float*)d_in[4];  // [256,512]
    const float* ab   = (const float*)d_in[5];  // [256]
    float* out = (float*)d_out;

    char* ws = (char*)d_ws;
    float* m            = (float*)(ws + 0);                 //  8 KB [8][256]
    float* dinv         = (float*)(ws + 8192);              //  8 KB [8][256]
    unsigned short* wb  = (unsigned short*)(ws + 16384);    // 1.18 MB [9][256][256]
    unsigned short* xpb = (unsigned short*)(ws + 1196032);  // 17.8 MB [8][66][66][256]

    k_style<<<64, 256, 0, stream>>>(s, aw, ab, m);
    k_prep<<<COUT + BS * HP, 256, 0, stream>>>(w, m, x, wb, dinv, xpb);
    k_conv<<<256, 512, 0, stream>>>(xpb, wb, dinv, bias, out);
}

// Round 9
// 138.477 us; speedup vs baseline: 1.2417x; 1.0332x over previous
//
#include <hip/hip_runtime.h>
#include <hip/hip_bf16.h>
#include <stdint.h>

// Problem constants
#define BS   8
#define CIN  256
#define COUT 256
#define SD   512
#define HH   64
#define WW   64
#define HP   66   // padded spatial dim

typedef __attribute__((ext_vector_type(8))) short short8;
typedef __attribute__((ext_vector_type(4))) float f32x4;

__device__ __forceinline__ unsigned short f2bf(float f) {
    __hip_bfloat16 h = __float2bfloat16(f);
    return *reinterpret_cast<unsigned short*>(&h);
}

typedef __attribute__((address_space(3))) unsigned int lds_u32_t;
typedef const __attribute__((address_space(1))) unsigned int glb_u32_t;

__device__ __forceinline__ void async16(const void* g, void* l) {
    __builtin_amdgcn_global_load_lds((glb_u32_t*)g, (lds_u32_t*)l, 16, 0, 0);
}

// ---------------------------------------------------------------------------
// K1: m[b,i] = s[b,:].aw[i,:] + ab[i] + 1
__global__ void k_style(const float* __restrict__ s, const float* __restrict__ aw,
                        const float* __restrict__ ab, float* __restrict__ m) {
    int b = blockIdx.x >> 3, chunk = blockIdx.x & 7;
    int tid = threadIdx.x;
    __shared__ float sv[SD];
    for (int d = tid; d < SD; d += 256) sv[d] = s[b * SD + d];
    __syncthreads();
    int il = tid >> 3, p = tid & 7;
    int i = chunk * 32 + il;
    const float4* awr = (const float4*)(aw + (size_t)i * SD + p * 64);
    float acc = 0.f;
#pragma unroll
    for (int d4 = 0; d4 < 16; ++d4) {
        float4 w4 = awr[d4];
        int d0 = p * 64 + d4 * 4;
        acc += w4.x * sv[d0] + w4.y * sv[d0 + 1] + w4.z * sv[d0 + 2] + w4.w * sv[d0 + 3];
    }
    acc += __shfl_xor(acc, 1);
    acc += __shfl_xor(acc, 2);
    acc += __shfl_xor(acc, 4);
    if (p == 0) m[b * CIN + i] = acc + ab[i] + 1.0f;
}

// ---------------------------------------------------------------------------
// K2: merged prep. Blocks [0,256): weight repack + dinv. Blocks [256,784):
// x modulate + NCHW fp32 -> zero-padded NHWC bf16 transpose.
// Round 9: transpose thread mapping swapped to make STORES coalesced.
// Old: x0=(u&15)*4, i0=(u>>4)*8 -> consecutive lanes varied x0 -> 16B
// stores at 512B stride (16B used per 64B sector, ~4x write amplification).
// New: i0=(u&31)*8, x0=(u>>5)*4 -> 32 consecutive lanes share x0 and span
// all 256 channels -> each (x0+j) row gets 32 x 16B = 512B contiguous
// stores (2KB per j-quad). Reads become lane-strided (32KB apart) but the
// 16 x-groups of the same (b,y) re-touch the same 64B lines within one
// block -> L1/L2 absorb the over-fetch; HBM fetch unchanged (~33.5MB).
// Arithmetic identical, only thread<->work mapping changed.
__global__ void k_prep(const float* __restrict__ w, const float* __restrict__ m,
                       const float* __restrict__ x,
                       unsigned short* __restrict__ wb, float* __restrict__ dinv,
                       unsigned short* __restrict__ xp) {
    __shared__ float red[4][8];
    int tid = threadIdx.x;

    if (blockIdx.x < COUT) {
        int o = blockIdx.x, i = tid;
        const float* wp = w + ((size_t)o * CIN + i) * 9;
        float v[9];
        float q = 0.f;
#pragma unroll
        for (int t = 0; t < 9; ++t) { v[t] = wp[t]; q += v[t] * v[t]; }
#pragma unroll
        for (int t = 0; t < 9; ++t)
            wb[((size_t)t * COUT + o) * CIN + i] = f2bf(v[t]);

        float r[8];
#pragma unroll
        for (int b = 0; b < 8; ++b) {
            float mv = m[b * CIN + i];
            r[b] = q * mv * mv;
        }
#pragma unroll
        for (int b = 0; b < 8; ++b) {
            r[b] += __shfl_xor(r[b], 1);
            r[b] += __shfl_xor(r[b], 2);
            r[b] += __shfl_xor(r[b], 4);
            r[b] += __shfl_xor(r[b], 8);
            r[b] += __shfl_xor(r[b], 16);
            r[b] += __shfl_xor(r[b], 32);
        }
        int lane = i & 63, wid = i >> 6;
        if (lane == 0) {
#pragma unroll
            for (int b = 0; b < 8; ++b) red[wid][b] = r[b];
        }
        __syncthreads();
        if (i < 8) {
            float acc = red[0][i] + red[1][i] + red[2][i] + red[3][i];
            dinv[i * COUT + o] = rsqrtf(acc + 1e-8f);
        }
        return;
    }

    int bi = blockIdx.x - COUT;
    int b = bi / HP, yp = bi % HP;
    unsigned short* row = xp + ((size_t)(b * HP + yp)) * HP * CIN;

    if (yp == 0 || yp == HP - 1) {
        uint4 z = {0u, 0u, 0u, 0u};
        uint4* r = (uint4*)row;
        for (int j = tid; j < HP * CIN / 8; j += 256) r[j] = z;
        return;
    }
    int y = yp - 1;

    if (tid < 64) {
        uint4 z = {0u, 0u, 0u, 0u};
        if (tid < 32) ((uint4*)row)[tid] = z;
        else ((uint4*)(row + (size_t)(HP - 1) * CIN))[tid - 32] = z;
    }

#pragma unroll
    for (int it = 0; it < 2; ++it) {
        int u = it * 256 + tid;
        int i0 = (u & 31) * 8;     // 32 ch-groups: consecutive lanes -> consecutive channels
        int x0 = (u >> 5) * 4;     // 16 x-groups
        float vv[8][4];
        float mv[8];
#pragma unroll
        for (int k = 0; k < 8; ++k) {
            *(float4*)vv[k] = *(const float4*)&x[(((size_t)b * CIN + i0 + k) * HH + y) * WW + x0];
            mv[k] = m[b * CIN + i0 + k];
        }
#pragma unroll
        for (int j = 0; j < 4; ++j) {
            short8 p;
#pragma unroll
            for (int k = 0; k < 8; ++k)
                p[k] = (short)f2bf(vv[k][j] * mv[k]);
            *(short8*)&row[(size_t)(x0 + j + 1) * CIN + i0] = p;
        }
    }
}

// ---------------------------------------------------------------------------
// K3: implicit GEMM conv, 256m x 64n tile (vmem-byte minimized).
// REVERTED to the session-best baseline (measured 43.8-44.6us, MfmaUtil ~34%).
// Six pipelining restructures (counted vmcnt, reg double-buffer x3,
// barrier-free direct-B, all-taps-B LDS) all measured neutral-to-worse:
// the per-tap barrier + 8-wave lockstep is a stable attractor at
// ~2900cy/tap, and register-pipeline variants spill (allocator caps at
// 128 VGPR). Keeping the known-best structure; this round's experiment
// is in k_prep.
// Grid 512 = 128 M-tiles x 4 N-tiles; same-M tiles land on the same XCD
// (bx%8 == mt%8), so per-XCD A slice (~2.2MB) + B (1.2MB) stay L2-resident.
// 4 waves stacked in m: wave w = image row y0+w, 64 n cols, full K.
// A: single LDS buffer [6 rows][66 cols][64ch], restaged per kc (4x).
// B: TRIPLE-buffered 8KB taps, prefetch depth 2, one barrier per tap.
__global__ void __launch_bounds__(256, 2)
k_conv(const unsigned short* __restrict__ xp,
       const unsigned short* __restrict__ wb,
       const float* __restrict__ dinv,
       const float* __restrict__ bias,
       float* __restrict__ out) {
    __shared__ unsigned short Ar[3168 * 8];      // 50688 B: [6 rows][66 cols][8 x 16B]
    __shared__ unsigned short Bs[3 * 512 * 8];   // 24576 B: 3 bufs x [64 rows][8 x 16B]

    int bx = blockIdx.x;
    int mt = bx & 127;
    int n0 = (bx >> 7) << 6;      // 4 N-tiles of 64
    int m0 = mt << 8;             // 256 m per tile
    int b  = m0 >> 12;
    int y0 = (m0 >> 6) & 63;      // image row base (tile = rows y0..y0+3)

    int tid = threadIdx.x;
    int lane = tid & 63, w = tid >> 6;
    int quad = lane >> 4, mrow = lane & 15;

    f32x4 acc[4][4] = {};

    const unsigned short* xb = xp + (size_t)b * HP * HP * CIN;

    auto stageA = [&](int kc) {
        int ch0 = kc * 64;
#pragma unroll
        for (int k = 0; k < 12; ++k) {
            int sA = k * 256 + tid;
            int rowA = sA / 528;
            int rem = sA - rowA * 528;
            int colA = rem >> 3, c4 = rem & 7;
            async16(xb + ((size_t)(y0 + rowA) * HP + colA) * CIN + ch0 + ((c4 ^ (colA & 7)) << 3),
                    &Ar[sA * 8]);
        }
        if (tid < 96) {   // tail: 3168 - 3072
            int sA = 3072 + tid;
            int rowA = sA / 528;
            int rem = sA - rowA * 528;
            int colA = rem >> 3, c4 = rem & 7;
            async16(xb + ((size_t)(y0 + rowA) * HP + colA) * CIN + ch0 + ((c4 ^ (colA & 7)) << 3),
                    &Ar[sA * 8]);
        }
    };

    auto stageB = [&](int tt, int kcc, int buf) {
        const unsigned short* bp = wb + ((size_t)tt * COUT + n0) * CIN + kcc * 64;
        unsigned short* dst = Bs + buf * 4096;
#pragma unroll
        for (int k = 0; k < 2; ++k) {
            int sB = k * 256 + tid;
            int rowB = sB >> 3, c4 = sB & 7;
            async16(bp + (size_t)rowB * CIN + ((c4 ^ (rowB & 7)) << 3), dst + sB * 8);
        }
    };

    stageA(0);
    stageB(0, 0, 0);
    stageB(1, 0, 1);
    __syncthreads();

#pragma unroll 1
    for (int kc = 0; kc < 4; ++kc) {
#pragma unroll
        for (int t = 0; t < 9; ++t) {
            // prefetch B two taps ahead (buf index (g+2)%3 folds at compile time)
            if (t < 7) stageB(t + 2, kc, (t + 2) % 3);
            else if (kc < 3) stageB(t - 7, kc + 1, (t + 2) % 3);

            int dy = t / 3, dx = t - dy * 3;
            int arow = w + dy;
            const unsigned short* Bcur = Bs + (t % 3) * 4096;

            short8 af[2][4], bf[2][4];
#pragma unroll
            for (int h = 0; h < 2; ++h)
#pragma unroll
                for (int i = 0; i < 4; ++i) {
                    int col = mrow + i * 16 + dx;
                    int chunk = arow * 528 + col * 8 + ((h * 4 + quad) ^ (col & 7));
                    af[h][i] = *(const short8*)&Ar[chunk * 8];
                }
#pragma unroll
            for (int h = 0; h < 2; ++h)
#pragma unroll
                for (int j = 0; j < 4; ++j) {
                    int rowB = mrow + j * 16;
                    int chunk = rowB * 8 + ((h * 4 + quad) ^ (rowB & 7));
                    bf[h][j] = *(const short8*)&Bcur[chunk * 8];
                }
#pragma unroll
            for (int h = 0; h < 2; ++h)
#pragma unroll
                for (int i = 0; i < 4; ++i)
#pragma unroll
                    for (int j = 0; j < 4; ++j)
                        acc[i][j] = __builtin_amdgcn_mfma_f32_16x16x32_bf16(
                            af[h][i], bf[h][j], acc[i][j], 0, 0, 0);

            __syncthreads();
            if (t == 8 && kc < 3) {   // A single-buffer restage (exposed, 3x)
                stageA(kc + 1);
                __syncthreads();
            }
        }
    }

    // ---- Epilogue: *dinv + bias. Wave w owns image row y0+w.
    // C/D layout: n(col) = mrow, x = quad*4 + reg + i*16.
    int y = y0 + w;
#pragma unroll
    for (int j = 0; j < 4; ++j) {
        int o = n0 + mrow + j * 16;
        float dv = dinv[b * COUT + o];
        float bv = bias[o];
#pragma unroll
        for (int i = 0; i < 4; ++i) {
            int xx = i * 16 + quad * 4;
            f32x4 v = acc[i][j] * dv + bv;
            *(f32x4*)(out + (((size_t)(b * COUT + o) * HH + y) * WW + xx)) = v;
        }
    }
}

// ---------------------------------------------------------------------------
extern "C" void kernel_launch(void* const* d_in, const int* in_sizes, int n_in,
                              void* d_out, int out_size, void* d_ws, size_t ws_size,
                              hipStream_t stream) {
    const float* x    = (const float*)d_in[0];  // [8,256,64,64]
    const float* s    = (const float*)d_in[1];  // [8,512]
    const float* w    = (const float*)d_in[2];  // [256,256,3,3]
    const float* bias = (const float*)d_in[3];  // [256,1,1]
    const float* aw   = (const float*)d_in[4];  // [256,512]
    const float* ab   = (const float*)d_in[5];  // [256]
    float* out = (float*)d_out;

    char* ws = (char*)d_ws;
    float* m            = (float*)(ws + 0);                 //  8 KB [8][256]
    float* dinv         = (float*)(ws + 8192);              //  8 KB [8][256]
    unsigned short* wb  = (unsigned short*)(ws + 16384);    // 1.18 MB [9][256][256]
    unsigned short* xpb = (unsigned short*)(ws + 1196032);  // 17.8 MB [8][66][66][256]

    k_style<<<64, 256, 0, stream>>>(s, aw, ab, m);
    k_prep<<<COUT + BS * HP, 256, 0, stream>>>(w, m, x, wb, dinv, xpb);
    k_conv<<<512, 256, 0, stream>>>(xpb, wb, dinv, bias, out);
}